// Round 3
// baseline (419.909 us; speedup 1.0000x reference)
//
#include <hip/hip_runtime.h>
#include <hip/hip_bf16.h>
#include <stdint.h>

typedef __bf16 bf16x8 __attribute__((ext_vector_type(8)));
typedef float f32x4 __attribute__((ext_vector_type(4)));

#define AS3 __attribute__((address_space(3)))
#define AS1 __attribute__((address_space(1)))

static __device__ __forceinline__ unsigned short f2bf(float f) {
  unsigned int u = __float_as_uint(f);
  u += 0x7FFF + ((u >> 16) & 1);   // round-to-nearest-even
  return (unsigned short)(u >> 16);
}

// ---------------- fp32 -> bf16 conversion kernels ----------------

extern "C" __global__ void cvt_bf16_kernel(const float* __restrict__ src,
                                           unsigned short* __restrict__ dst,
                                           long n4) {
  long i = (long)blockIdx.x * blockDim.x + threadIdx.x;
  const long stride = (long)gridDim.x * blockDim.x;
  for (; i < n4; i += stride) {
    const float4 v = ((const float4*)src)[i];
    ushort4 o;
    o.x = f2bf(v.x); o.y = f2bf(v.y); o.z = f2bf(v.z); o.w = f2bf(v.w);
    ((ushort4*)dst)[i] = o;
  }
}

extern "C" __global__ void cvt_pad_kernel(const float* __restrict__ src,
                                          unsigned short* __restrict__ dst,
                                          long nsrc4, long ntot4) {
  long i = (long)blockIdx.x * blockDim.x + threadIdx.x;
  const long stride = (long)gridDim.x * blockDim.x;
  for (; i < ntot4; i += stride) {
    ushort4 o = {0, 0, 0, 0};
    if (i < nsrc4) {
      const float4 v = ((const float4*)src)[i];
      o.x = f2bf(v.x); o.y = f2bf(v.y); o.z = f2bf(v.z); o.w = f2bf(v.w);
    }
    ((ushort4*)dst)[i] = o;
  }
}

// ============ 256x256 8-phase bf16 NT GEMM (C = A * Bw^T), BK=64 ============
// 8 waves (2M x 4N), wave tile 128x64 (row-halves interleaved: wave wm owns
// rows wm*64..+64 of A-half0 and of A-half1; wave wn owns cols wn*64..+64,
// where B LDS halves interleave 32-col groups so quadrant c maps to B-half c).
// LDS: A[2buf][2half][128][64] = 64KB, B same at +64KB -> 128KB total.
// Per K-tile: 4 phases (quadrants (0,0),(0,1),(1,1),(1,0)); each phase:
//   {ds_reads for this quadrant; stage one half-tile; barrier; lgkmcnt(0);
//    setprio(1); 16 MFMA; setprio(0); barrier}
// Staging schedule (earliest-legal, one half-tile per phase):
//   p0: A1 of kt+1 | p1: B0 of kt+1 | p2: A0 of kt+2 | p3: B1 of kt+2
//   p4: A1 of kt+2 | p5: B0 of kt+2 | p6: A0 of kt+3 | p7: B1 of kt+3
// vmcnt(4) BEFORE the end-barrier of p3/p7 (wait-then-barrier => after the
// barrier every wave's stages except the 2 newest half-tiles have landed,
// which is exactly the next K-tile's full set). Last iteration: vmcnt(0).
// Swizzle: LDS linear (global_load_lds), global source k16-chunk ^= row&7,
// ds_read applies same XOR -> 2-way max bank aliasing (free).

template <int MODE>
__global__ __launch_bounds__(512, 2)
void mla_gemm(const __hip_bfloat16* __restrict__ A0p,
              const __hip_bfloat16* __restrict__ B0p, int K0,
              const __hip_bfloat16* __restrict__ A1p,
              const __hip_bfloat16* __restrict__ B1p,
              unsigned short* __restrict__ qlora,
              const float* __restrict__ cosp,
              const float* __restrict__ sinp,
              float* __restrict__ out) {
  extern __shared__ __align__(128) char lds[];
  const int tid = threadIdx.x;
  const int lane = tid & 63;
  const int w = tid >> 6;
  const int wm = w >> 2, wn = w & 3;
  const int l15 = lane & 15, lhi = lane >> 4;
  const int srow8 = lane >> 3;
  const int swzc = ((lane & 7) ^ srow8) * 8;   // swizzled source chunk (elements)

  const __hip_bfloat16* Aptr;
  const __hip_bfloat16* Bptr;
  int K, bm, bn;
  bool isA2 = false;
  if constexpr (MODE == 0) {
    const int swz = ((int)blockIdx.x & 7) * 32 + ((int)blockIdx.x >> 3);
    bm = swz >> 3; bn = swz & 7;
    Aptr = A0p; Bptr = B0p; K = K0;
  } else {
    const int bid = (int)blockIdx.x;
    if (bid < 32) {  // k_pe slice: x @ w1 cols 2048.. (K=4096), independent of q_lora
      isA2 = true; bm = bid; bn = 8; Aptr = A1p; Bptr = B1p; K = 4096;
    } else {
      const int b2 = bid - 32;
      const int swz = (b2 & 7) * 96 + (b2 >> 3);
      bm = swz / 24; bn = swz - bm * 24;
      Aptr = A0p; Bptr = B0p; K = K0;
    }
  }
  const long brow = (long)bm * 256;
  const int bcol = bn * 256;

  // staging pointers (per-lane global source, chunk pre-swizzled)
  const __hip_bfloat16* aSt = Aptr + (brow + w * 16 + srow8) * (long)K + swzc;
  const __hip_bfloat16* bSt = Bptr + ((long)bcol + srow8) * (long)K + swzc;
  const int wj0 = w * 16, wj1 = w * 16 + 8;
  const int cb_j0 = (2 * (wj0 >> 5)) * 32 + (wj0 & 31);  // B col base, h adds 32
  const int cb_j1 = (2 * (wj1 >> 5)) * 32 + (wj1 & 31);
  const int ldsWj = w * 2048;

  // fragment-read geometry
  const int aRdRow = (wm * 64 + l15) * 128;
  const int bRdRow = (wn * 32 + l15) * 128;
  const int ck0 = (lhi ^ (l15 & 7)) * 16;     // kk=1: ck0 ^ 64

  f32x4 acc[8][4] = {};
  bf16x8 aF[4][2];
  bf16x8 bF[2][2][2];  // [c][fq][kk]

  const int T = K >> 6;
  const int I = T >> 1;

  auto stage = [&](int u, int kt) {
    const int b = kt & 1;
    if (u < 2) {  // A half u
      const int off = b * 32768 + u * 16384 + ldsWj;
      __builtin_amdgcn_global_load_lds((AS1 void*)(aSt + (long)(u * 128) * K + kt * 64),
                                       (AS3 void*)(lds + off), 16, 0, 0);
      __builtin_amdgcn_global_load_lds((AS1 void*)(aSt + (long)(u * 128 + 8) * K + kt * 64),
                                       (AS3 void*)(lds + off + 1024), 16, 0, 0);
    } else {      // B half u-2 (32-col interleaved halves)
      const int h = u - 2;
      const int off = 65536 + b * 32768 + h * 16384 + ldsWj;
      __builtin_amdgcn_global_load_lds((AS1 void*)(bSt + (long)(cb_j0 + h * 32) * K + kt * 64),
                                       (AS3 void*)(lds + off), 16, 0, 0);
      __builtin_amdgcn_global_load_lds((AS1 void*)(bSt + (long)(cb_j1 + h * 32) * K + kt * 64),
                                       (AS3 void*)(lds + off + 1024), 16, 0, 0);
    }
  };
  auto readA = [&](int qh, int b) {
    const int base = b * 32768 + qh * 16384 + aRdRow;
    #pragma unroll
    for (int fr = 0; fr < 4; ++fr) {
      aF[fr][0] = *(const bf16x8*)(lds + base + fr * 2048 + ck0);
      aF[fr][1] = *(const bf16x8*)(lds + base + fr * 2048 + (ck0 ^ 64));
    }
  };
  auto readB = [&](int c, int b) {
    const int base = 65536 + b * 32768 + c * 16384 + bRdRow;
    #pragma unroll
    for (int fq = 0; fq < 2; ++fq) {
      bF[c][fq][0] = *(const bf16x8*)(lds + base + fq * 2048 + ck0);
      bF[c][fq][1] = *(const bf16x8*)(lds + base + fq * 2048 + (ck0 ^ 64));
    }
  };
  auto mmac = [&](int qh, int c) {
    __builtin_amdgcn_s_setprio(1);
    #pragma unroll
    for (int fr = 0; fr < 4; ++fr)
      #pragma unroll
      for (int fq = 0; fq < 2; ++fq) {
        acc[qh * 4 + fr][c * 2 + fq] = __builtin_amdgcn_mfma_f32_16x16x32_bf16(
            aF[fr][0], bF[c][fq][0], acc[qh * 4 + fr][c * 2 + fq], 0, 0, 0);
        acc[qh * 4 + fr][c * 2 + fq] = __builtin_amdgcn_mfma_f32_16x16x32_bf16(
            aF[fr][1], bF[c][fq][1], acc[qh * 4 + fr][c * 2 + fq], 0, 0, 0);
      }
    __builtin_amdgcn_s_setprio(0);
  };
  #define BAR() __builtin_amdgcn_s_barrier()
  #define LGKM0() asm volatile("s_waitcnt lgkmcnt(0)" ::: "memory")

  // prologue: kt0 {A0,A1,B0,B1} then kt1 {A0,B1}; wait first 4 landed
  stage(0, 0); stage(1, 0); stage(2, 0); stage(3, 0);
  stage(0, 1); stage(3, 1);
  asm volatile("s_waitcnt vmcnt(4)" ::: "memory");
  BAR();

  for (int i = 0; i < I; ++i) {
    const int ktB = 2 * i + 1;
    const bool more = (i < I - 1);
    // p0 (buf0, q=0,0)
    readA(0, 0); readB(0, 0); stage(1, ktB);
    BAR(); LGKM0(); mmac(0, 0); BAR();
    // p1 (q=0,1)
    readB(1, 0); stage(2, ktB);
    BAR(); LGKM0(); mmac(0, 1); BAR();
    // p2 (q=1,1)
    readA(1, 0); if (more) stage(0, ktB + 1);
    BAR(); LGKM0(); mmac(1, 1); BAR();
    // p3 (q=1,0)  [B c0 held from p0]
    if (more) stage(3, ktB + 1);
    BAR(); LGKM0(); mmac(1, 0);
    if (more) asm volatile("s_waitcnt vmcnt(4)" ::: "memory");
    else      asm volatile("s_waitcnt vmcnt(0)" ::: "memory");
    BAR();
    // p4 (buf1, q=0,0)
    readA(0, 1); readB(0, 1); if (more) stage(1, ktB + 1);
    BAR(); LGKM0(); mmac(0, 0); BAR();
    // p5 (q=0,1)
    readB(1, 1); if (more) stage(2, ktB + 1);
    BAR(); LGKM0(); mmac(0, 1); BAR();
    // p6 (q=1,1)
    readA(1, 1); if (more) stage(0, ktB + 2);
    BAR(); LGKM0(); mmac(1, 1); BAR();
    // p7 (q=1,0)
    if (more) stage(3, ktB + 2);
    BAR(); LGKM0(); mmac(1, 0);
    if (more) asm volatile("s_waitcnt vmcnt(4)" ::: "memory");
    else      asm volatile("s_waitcnt vmcnt(0)" ::: "memory");
    BAR();
  }

  // ---- epilogue ----
  // row(i8,r) = brow + (i8>>2)*128 + wm*64 + (i8&3)*16 + lhi*4 + r
  // col(j)    = bcol + wn*64 + (j>>1)*32 + (j&1)*16 + l15
  const int wcol = bcol + wn * 64;
  const long rb = brow + wm * 64 + lhi * 4;

  if constexpr (MODE == 0) {
    if (wcol < 1536) {  // q_lora (bf16, row stride 1536)
      #pragma unroll
      for (int i8 = 0; i8 < 8; ++i8)
        #pragma unroll
        for (int r = 0; r < 4; ++r) {
          const long row = rb + (i8 >> 2) * 128 + (i8 & 3) * 16 + r;
          #pragma unroll
          for (int j = 0; j < 4; ++j)
            qlora[row * 1536 + wcol + (j >> 1) * 32 + (j & 1) * 16 + l15] =
                f2bf(acc[i8][j][r]);
        }
    } else {            // compressed_kv -> out cols 6208 + (col-1536)
      #pragma unroll
      for (int i8 = 0; i8 < 8; ++i8)
        #pragma unroll
        for (int r = 0; r < 4; ++r) {
          const long row = rb + (i8 >> 2) * 128 + (i8 & 3) * 16 + r;
          #pragma unroll
          for (int j = 0; j < 4; ++j)
            out[row * 6720 + wcol + 4672 + (j >> 1) * 32 + (j & 1) * 16 + l15] =
                acc[i8][j][r];
        }
    }
  } else {
    if (isA2) {
      if (wn == 0) {    // cols 2048..2111 -> k_pe + RoPE -> out 6144..6207
        #pragma unroll
        for (int i8 = 0; i8 < 8; ++i8)
          #pragma unroll
          for (int r = 0; r < 4; ++r) {
            const long row = rb + (i8 >> 2) * 128 + (i8 & 3) * 16 + r;
            #pragma unroll
            for (int j = 0; j < 4; ++j) {
              const int d = (j >> 1) * 32 + (j & 1) * 16 + l15;
              const float v = acc[i8][j][r];
              const float rot = (j < 2) ? -acc[i8][j + 2][r] : acc[i8][j - 2][r];
              out[row * 6720 + 6144 + d] = v * cosp[row * 64 + d] + rot * sinp[row * 64 + d];
            }
          }
      }                 // wn 1..3: pad cols, dropped
    } else if ((wcol % 192) != 128) {  // q_nope: plain copy
      #pragma unroll
      for (int i8 = 0; i8 < 8; ++i8)
        #pragma unroll
        for (int r = 0; r < 4; ++r) {
          const long row = rb + (i8 >> 2) * 128 + (i8 & 3) * 16 + r;
          #pragma unroll
          for (int j = 0; j < 4; ++j)
            out[row * 6720 + wcol + (j >> 1) * 32 + (j & 1) * 16 + l15] = acc[i8][j][r];
        }
    } else {            // q_pe 64-block: RoPE (d pairs with d+-32 => j^2, same lane)
      #pragma unroll
      for (int i8 = 0; i8 < 8; ++i8)
        #pragma unroll
        for (int r = 0; r < 4; ++r) {
          const long row = rb + (i8 >> 2) * 128 + (i8 & 3) * 16 + r;
          #pragma unroll
          for (int j = 0; j < 4; ++j) {
            const int d = (j >> 1) * 32 + (j & 1) * 16 + l15;
            const float v = acc[i8][j][r];
            const float rot = (j < 2) ? -acc[i8][j + 2][r] : acc[i8][j - 2][r];
            out[row * 6720 + wcol + d] = v * cosp[row * 64 + d] + rot * sinp[row * 64 + d];
          }
        }
    }
  }
  #undef BAR
  #undef LGKM0
}

// ---------------- launch ----------------

extern "C" void kernel_launch(void* const* d_in, const int* in_sizes, int n_in,
                              void* d_out, int out_size, void* d_ws, size_t ws_size,
                              hipStream_t stream) {
  const float* x    = (const float*)d_in[0];
  const float* cosp = (const float*)d_in[1];
  const float* sinp = (const float*)d_in[2];
  const float* Wqa  = (const float*)d_in[3];
  const float* Wqb  = (const float*)d_in[4];
  const float* Wkva = (const float*)d_in[5];
  float* out = (float*)d_out;

  char* ws = (char*)d_ws;
  // ws: x_bf16 64MB | w1 (Wqa 0..1535 | Wkva 1536..2111 | pad..2175) 17MB |
  //     wqb 18MB | q_lora 24MB   (A2 blocks read ~1MB past w1 into wqb: benign,
  //     deterministic, results dropped in epilogue)
  __hip_bfloat16* xb  = (__hip_bfloat16*)ws;
  __hip_bfloat16* w1  = (__hip_bfloat16*)(ws + 67108864L);
  __hip_bfloat16* wqb = (__hip_bfloat16*)(ws + 67108864L + 17825792L);
  unsigned short* ql  = (unsigned short*)(ws + 67108864L + 17825792L + 18874368L);

  cvt_bf16_kernel<<<2048, 256, 0, stream>>>(x,   (unsigned short*)xb,  8192L * 4096 / 4);
  cvt_bf16_kernel<<<1024, 256, 0, stream>>>(Wqa, (unsigned short*)w1,  1536L * 4096 / 4);
  cvt_pad_kernel<<<640, 256, 0, stream>>>(Wkva, (unsigned short*)(w1 + 1536L * 4096),
                                          576L * 4096 / 4, 640L * 4096 / 4);
  cvt_bf16_kernel<<<1024, 256, 0, stream>>>(Wqb, (unsigned short*)wqb, 6144L * 1536 / 4);

  (void)hipFuncSetAttribute((const void*)&mla_gemm<0>,
                            hipFuncAttributeMaxDynamicSharedMemorySize, 131072);
  (void)hipFuncSetAttribute((const void*)&mla_gemm<1>,
                            hipFuncAttributeMaxDynamicSharedMemorySize, 131072);

  // launch1: x @ w1[0:2048] -> q_lora + compressed_kv. 32x8 = 256 blocks (1 round).
  mla_gemm<0><<<dim3(256), 512, 131072, stream>>>(xb, w1, 4096, nullptr, nullptr,
                                                  ql, cosp, sinp, out);
  // launch2: 32 k_pe blocks (x @ w1 cols 2048.., K=4096) + 768 q blocks
  // (q_lora @ wqb, K=1536). 800 blocks, dynamically balanced.
  mla_gemm<1><<<dim3(800), 512, 131072, stream>>>((const __hip_bfloat16*)ql, wqb, 1536,
                                                  xb, w1, ql, cosp, sinp, out);
}

// Round 5
// 405.845 us; speedup vs baseline: 1.0347x; 1.0347x over previous
//
#include <hip/hip_runtime.h>
#include <hip/hip_bf16.h>
#include <stdint.h>

typedef __bf16 bf16x8 __attribute__((ext_vector_type(8)));
typedef float f32x4 __attribute__((ext_vector_type(4)));
typedef float fvec4 __attribute__((ext_vector_type(4)));
typedef unsigned short usvec4 __attribute__((ext_vector_type(4)));

#define AS3 __attribute__((address_space(3)))
#define AS1 __attribute__((address_space(1)))

static __device__ __forceinline__ unsigned short f2bf(float f) {
  unsigned int u = __float_as_uint(f);
  u += 0x7FFF + ((u >> 16) & 1);   // round-to-nearest-even
  return (unsigned short)(u >> 16);
}

// ---------------- fp32 -> bf16 conversion kernels ----------------

extern "C" __global__ void cvt_bf16_kernel(const float* __restrict__ src,
                                           unsigned short* __restrict__ dst,
                                           long n4) {
  long i = (long)blockIdx.x * blockDim.x + threadIdx.x;
  const long stride = (long)gridDim.x * blockDim.x;
  for (; i < n4; i += stride) {
    const fvec4 v = __builtin_nontemporal_load(&((const fvec4*)src)[i]);
    usvec4 o;
    o.x = f2bf(v.x); o.y = f2bf(v.y); o.z = f2bf(v.z); o.w = f2bf(v.w);
    ((usvec4*)dst)[i] = o;
  }
}

extern "C" __global__ void cvt_pad_kernel(const float* __restrict__ src,
                                          unsigned short* __restrict__ dst,
                                          long nsrc4, long ntot4) {
  long i = (long)blockIdx.x * blockDim.x + threadIdx.x;
  const long stride = (long)gridDim.x * blockDim.x;
  for (; i < ntot4; i += stride) {
    usvec4 o = {0, 0, 0, 0};
    if (i < nsrc4) {
      const fvec4 v = __builtin_nontemporal_load(&((const fvec4*)src)[i]);
      o.x = f2bf(v.x); o.y = f2bf(v.y); o.z = f2bf(v.z); o.w = f2bf(v.w);
    }
    ((usvec4*)dst)[i] = o;
  }
}

// ============ 256x256 8-phase bf16 NT GEMM (C = A * Bw^T), BK=64 ============
// Structure identical to round 3 (8 waves 2Mx4N, wave tile 128x64, 2-buf LDS,
// counted vmcnt(4), both-sides k16^row&7 swizzle). Changes this round:
//  - all `out` stores are NON-TEMPORAL (output is write-once; stop L3 thrash
//    that was evicting wqb/ql and exposing HBM latency in the K-loop)
//  - sched_barrier(0) after each lgkmcnt(0) (rule #18)

template <int MODE>
__global__ __launch_bounds__(512, 2)
void mla_gemm(const __hip_bfloat16* __restrict__ A0p,
              const __hip_bfloat16* __restrict__ B0p, int K0,
              const __hip_bfloat16* __restrict__ A1p,
              const __hip_bfloat16* __restrict__ B1p,
              unsigned short* __restrict__ qlora,
              const float* __restrict__ cosp,
              const float* __restrict__ sinp,
              float* __restrict__ out) {
  extern __shared__ __align__(128) char lds[];
  const int tid = threadIdx.x;
  const int lane = tid & 63;
  const int w = tid >> 6;
  const int wm = w >> 2, wn = w & 3;
  const int l15 = lane & 15, lhi = lane >> 4;
  const int srow8 = lane >> 3;
  const int swzc = ((lane & 7) ^ srow8) * 8;   // swizzled source chunk (elements)

  const __hip_bfloat16* Aptr;
  const __hip_bfloat16* Bptr;
  int K, bm, bn;
  bool isA2 = false;
  if constexpr (MODE == 0) {
    const int swz = ((int)blockIdx.x & 7) * 32 + ((int)blockIdx.x >> 3);
    bm = swz >> 3; bn = swz & 7;
    Aptr = A0p; Bptr = B0p; K = K0;
  } else {
    const int bid = (int)blockIdx.x;
    if (bid < 32) {  // k_pe slice: x @ w1 cols 2048.. (K=4096)
      isA2 = true; bm = bid; bn = 8; Aptr = A1p; Bptr = B1p; K = 4096;
    } else {
      const int b2 = bid - 32;
      const int swz = (b2 & 7) * 96 + (b2 >> 3);
      bm = swz / 24; bn = swz - bm * 24;
      Aptr = A0p; Bptr = B0p; K = K0;
    }
  }
  const long brow = (long)bm * 256;
  const int bcol = bn * 256;

  const __hip_bfloat16* aSt = Aptr + (brow + w * 16 + srow8) * (long)K + swzc;
  const __hip_bfloat16* bSt = Bptr + ((long)bcol + srow8) * (long)K + swzc;
  const int wj0 = w * 16, wj1 = w * 16 + 8;
  const int cb_j0 = (2 * (wj0 >> 5)) * 32 + (wj0 & 31);
  const int cb_j1 = (2 * (wj1 >> 5)) * 32 + (wj1 & 31);
  const int ldsWj = w * 2048;

  const int aRdRow = (wm * 64 + l15) * 128;
  const int bRdRow = (wn * 32 + l15) * 128;
  const int ck0 = (lhi ^ (l15 & 7)) * 16;

  f32x4 acc[8][4] = {};
  bf16x8 aF[4][2];
  bf16x8 bF[2][2][2];

  const int T = K >> 6;
  const int I = T >> 1;

  auto stage = [&](int u, int kt) {
    const int b = kt & 1;
    if (u < 2) {
      const int off = b * 32768 + u * 16384 + ldsWj;
      __builtin_amdgcn_global_load_lds((AS1 void*)(aSt + (long)(u * 128) * K + kt * 64),
                                       (AS3 void*)(lds + off), 16, 0, 0);
      __builtin_amdgcn_global_load_lds((AS1 void*)(aSt + (long)(u * 128 + 8) * K + kt * 64),
                                       (AS3 void*)(lds + off + 1024), 16, 0, 0);
    } else {
      const int h = u - 2;
      const int off = 65536 + b * 32768 + h * 16384 + ldsWj;
      __builtin_amdgcn_global_load_lds((AS1 void*)(bSt + (long)(cb_j0 + h * 32) * K + kt * 64),
                                       (AS3 void*)(lds + off), 16, 0, 0);
      __builtin_amdgcn_global_load_lds((AS1 void*)(bSt + (long)(cb_j1 + h * 32) * K + kt * 64),
                                       (AS3 void*)(lds + off + 1024), 16, 0, 0);
    }
  };
  auto readA = [&](int qh, int b) {
    const int base = b * 32768 + qh * 16384 + aRdRow;
    #pragma unroll
    for (int fr = 0; fr < 4; ++fr) {
      aF[fr][0] = *(const bf16x8*)(lds + base + fr * 2048 + ck0);
      aF[fr][1] = *(const bf16x8*)(lds + base + fr * 2048 + (ck0 ^ 64));
    }
  };
  auto readB = [&](int c, int b) {
    const int base = 65536 + b * 32768 + c * 16384 + bRdRow;
    #pragma unroll
    for (int fq = 0; fq < 2; ++fq) {
      bF[c][fq][0] = *(const bf16x8*)(lds + base + fq * 2048 + ck0);
      bF[c][fq][1] = *(const bf16x8*)(lds + base + fq * 2048 + (ck0 ^ 64));
    }
  };
  auto mmac = [&](int qh, int c) {
    __builtin_amdgcn_s_setprio(1);
    #pragma unroll
    for (int fr = 0; fr < 4; ++fr)
      #pragma unroll
      for (int fq = 0; fq < 2; ++fq) {
        acc[qh * 4 + fr][c * 2 + fq] = __builtin_amdgcn_mfma_f32_16x16x32_bf16(
            aF[fr][0], bF[c][fq][0], acc[qh * 4 + fr][c * 2 + fq], 0, 0, 0);
        acc[qh * 4 + fr][c * 2 + fq] = __builtin_amdgcn_mfma_f32_16x16x32_bf16(
            aF[fr][1], bF[c][fq][1], acc[qh * 4 + fr][c * 2 + fq], 0, 0, 0);
      }
    __builtin_amdgcn_s_setprio(0);
  };
  #define BAR() __builtin_amdgcn_s_barrier()
  #define LGKM0() do { asm volatile("s_waitcnt lgkmcnt(0)" ::: "memory"); \
                       __builtin_amdgcn_sched_barrier(0); } while (0)

  stage(0, 0); stage(1, 0); stage(2, 0); stage(3, 0);
  stage(0, 1); stage(3, 1);
  asm volatile("s_waitcnt vmcnt(4)" ::: "memory");
  BAR();

  for (int i = 0; i < I; ++i) {
    const int ktB = 2 * i + 1;
    const bool more = (i < I - 1);
    readA(0, 0); readB(0, 0); stage(1, ktB);
    BAR(); LGKM0(); mmac(0, 0); BAR();
    readB(1, 0); stage(2, ktB);
    BAR(); LGKM0(); mmac(0, 1); BAR();
    readA(1, 0); if (more) stage(0, ktB + 1);
    BAR(); LGKM0(); mmac(1, 1); BAR();
    if (more) stage(3, ktB + 1);
    BAR(); LGKM0(); mmac(1, 0);
    if (more) asm volatile("s_waitcnt vmcnt(4)" ::: "memory");
    else      asm volatile("s_waitcnt vmcnt(0)" ::: "memory");
    BAR();
    readA(0, 1); readB(0, 1); if (more) stage(1, ktB + 1);
    BAR(); LGKM0(); mmac(0, 0); BAR();
    readB(1, 1); if (more) stage(2, ktB + 1);
    BAR(); LGKM0(); mmac(0, 1); BAR();
    readA(1, 1); if (more) stage(0, ktB + 2);
    BAR(); LGKM0(); mmac(1, 1); BAR();
    if (more) stage(3, ktB + 2);
    BAR(); LGKM0(); mmac(1, 0);
    if (more) asm volatile("s_waitcnt vmcnt(4)" ::: "memory");
    else      asm volatile("s_waitcnt vmcnt(0)" ::: "memory");
    BAR();
  }

  // ---- epilogue ----
  // row(i8,r) = brow + (i8>>2)*128 + wm*64 + (i8&3)*16 + lhi*4 + r
  // col(j)    = bcol + wn*64 + (j>>1)*32 + (j&1)*16 + l15
  const int wcol = bcol + wn * 64;
  const long rb = brow + wm * 64 + lhi * 4;

  if constexpr (MODE == 0) {
    if (wcol < 1536) {  // q_lora (bf16, row stride 1536) — re-read next launch: cached
      #pragma unroll
      for (int i8 = 0; i8 < 8; ++i8)
        #pragma unroll
        for (int r = 0; r < 4; ++r) {
          const long row = rb + (i8 >> 2) * 128 + (i8 & 3) * 16 + r;
          #pragma unroll
          for (int j = 0; j < 4; ++j)
            qlora[row * 1536 + wcol + (j >> 1) * 32 + (j & 1) * 16 + l15] =
                f2bf(acc[i8][j][r]);
        }
    } else {            // compressed_kv -> out cols 6208 + (col-1536), NT
      #pragma unroll
      for (int i8 = 0; i8 < 8; ++i8)
        #pragma unroll
        for (int r = 0; r < 4; ++r) {
          const long row = rb + (i8 >> 2) * 128 + (i8 & 3) * 16 + r;
          #pragma unroll
          for (int j = 0; j < 4; ++j)
            __builtin_nontemporal_store(acc[i8][j][r],
                &out[row * 6720 + wcol + 4672 + (j >> 1) * 32 + (j & 1) * 16 + l15]);
        }
    }
  } else {
    if (isA2) {
      if (wn == 0) {    // k_pe + RoPE -> out 6144..6207, NT
        #pragma unroll
        for (int i8 = 0; i8 < 8; ++i8)
          #pragma unroll
          for (int r = 0; r < 4; ++r) {
            const long row = rb + (i8 >> 2) * 128 + (i8 & 3) * 16 + r;
            #pragma unroll
            for (int j = 0; j < 4; ++j) {
              const int d = (j >> 1) * 32 + (j & 1) * 16 + l15;
              const float v = acc[i8][j][r];
              const float rot = (j < 2) ? -acc[i8][j + 2][r] : acc[i8][j - 2][r];
              __builtin_nontemporal_store(
                  v * cosp[row * 64 + d] + rot * sinp[row * 64 + d],
                  &out[row * 6720 + 6144 + d]);
            }
          }
      }
    } else if ((wcol % 192) != 128) {  // q_nope: plain copy, NT
      #pragma unroll
      for (int i8 = 0; i8 < 8; ++i8)
        #pragma unroll
        for (int r = 0; r < 4; ++r) {
          const long row = rb + (i8 >> 2) * 128 + (i8 & 3) * 16 + r;
          #pragma unroll
          for (int j = 0; j < 4; ++j)
            __builtin_nontemporal_store(acc[i8][j][r],
                &out[row * 6720 + wcol + (j >> 1) * 32 + (j & 1) * 16 + l15]);
        }
    } else {            // q_pe 64-block: RoPE, NT
      #pragma unroll
      for (int i8 = 0; i8 < 8; ++i8)
        #pragma unroll
        for (int r = 0; r < 4; ++r) {
          const long row = rb + (i8 >> 2) * 128 + (i8 & 3) * 16 + r;
          #pragma unroll
          for (int j = 0; j < 4; ++j) {
            const int d = (j >> 1) * 32 + (j & 1) * 16 + l15;
            const float v = acc[i8][j][r];
            const float rot = (j < 2) ? -acc[i8][j + 2][r] : acc[i8][j - 2][r];
            __builtin_nontemporal_store(
                v * cosp[row * 64 + d] + rot * sinp[row * 64 + d],
                &out[row * 6720 + wcol + d]);
          }
        }
    }
  }
  #undef BAR
  #undef LGKM0
}

// ---------------- launch ----------------

extern "C" void kernel_launch(void* const* d_in, const int* in_sizes, int n_in,
                              void* d_out, int out_size, void* d_ws, size_t ws_size,
                              hipStream_t stream) {
  const float* x    = (const float*)d_in[0];
  const float* cosp = (const float*)d_in[1];
  const float* sinp = (const float*)d_in[2];
  const float* Wqa  = (const float*)d_in[3];
  const float* Wqb  = (const float*)d_in[4];
  const float* Wkva = (const float*)d_in[5];
  float* out = (float*)d_out;

  char* ws = (char*)d_ws;
  __hip_bfloat16* xb  = (__hip_bfloat16*)ws;
  __hip_bfloat16* w1  = (__hip_bfloat16*)(ws + 67108864L);
  __hip_bfloat16* wqb = (__hip_bfloat16*)(ws + 67108864L + 17825792L);
  unsigned short* ql  = (unsigned short*)(ws + 67108864L + 17825792L + 18874368L);

  cvt_bf16_kernel<<<2048, 256, 0, stream>>>(x,   (unsigned short*)xb,  8192L * 4096 / 4);
  cvt_bf16_kernel<<<1024, 256, 0, stream>>>(Wqa, (unsigned short*)w1,  1536L * 4096 / 4);
  cvt_pad_kernel<<<640, 256, 0, stream>>>(Wkva, (unsigned short*)(w1 + 1536L * 4096),
                                          576L * 4096 / 4, 640L * 4096 / 4);
  cvt_bf16_kernel<<<1024, 256, 0, stream>>>(Wqb, (unsigned short*)wqb, 6144L * 1536 / 4);

  (void)hipFuncSetAttribute((const void*)&mla_gemm<0>,
                            hipFuncAttributeMaxDynamicSharedMemorySize, 131072);
  (void)hipFuncSetAttribute((const void*)&mla_gemm<1>,
                            hipFuncAttributeMaxDynamicSharedMemorySize, 131072);

  // launch1: x @ w1[0:2048] -> q_lora + compressed_kv. 256 blocks (1 round).
  mla_gemm<0><<<dim3(256), 512, 131072, stream>>>(xb, w1, 4096, nullptr, nullptr,
                                                  ql, cosp, sinp, out);
  // launch2: 32 k_pe blocks (K=4096, dispatched first = LPT) + 768 q blocks (K=1536).
  mla_gemm<1><<<dim3(800), 512, 131072, stream>>>((const __hip_bfloat16*)ql, wqb, 1536,
                                                  xb, w1, ql, cosp, sinp, out);
}

// Round 6
// 362.596 us; speedup vs baseline: 1.1581x; 1.1193x over previous
//
#include <hip/hip_runtime.h>
#include <hip/hip_bf16.h>
#include <stdint.h>

typedef __bf16 bf16x8 __attribute__((ext_vector_type(8)));
typedef float f32x4 __attribute__((ext_vector_type(4)));
typedef float fvec4 __attribute__((ext_vector_type(4)));
typedef unsigned short usvec4 __attribute__((ext_vector_type(4)));
typedef unsigned int ui32x4 __attribute__((ext_vector_type(4)));

#define AS3 __attribute__((address_space(3)))
#define AS1 __attribute__((address_space(1)))

static __device__ __forceinline__ unsigned short f2bf(float f) {
  unsigned int u = __float_as_uint(f);
  u += 0x7FFF + ((u >> 16) & 1);   // round-to-nearest-even
  return (unsigned short)(u >> 16);
}

// ---------------- fp32 -> bf16 conversion kernels ----------------

extern "C" __global__ void cvt_bf16_kernel(const float* __restrict__ src,
                                           unsigned short* __restrict__ dst,
                                           long n4) {
  long i = (long)blockIdx.x * blockDim.x + threadIdx.x;
  const long stride = (long)gridDim.x * blockDim.x;
  for (; i < n4; i += stride) {
    const fvec4 v = __builtin_nontemporal_load(&((const fvec4*)src)[i]);
    usvec4 o;
    o.x = f2bf(v.x); o.y = f2bf(v.y); o.z = f2bf(v.z); o.w = f2bf(v.w);
    ((usvec4*)dst)[i] = o;
  }
}

extern "C" __global__ void cvt_pad_kernel(const float* __restrict__ src,
                                          unsigned short* __restrict__ dst,
                                          long nsrc4, long ntot4) {
  long i = (long)blockIdx.x * blockDim.x + threadIdx.x;
  const long stride = (long)gridDim.x * blockDim.x;
  for (; i < ntot4; i += stride) {
    usvec4 o = {0, 0, 0, 0};
    if (i < nsrc4) {
      const fvec4 v = __builtin_nontemporal_load(&((const fvec4*)src)[i]);
      o.x = f2bf(v.x); o.y = f2bf(v.y); o.z = f2bf(v.z); o.w = f2bf(v.w);
    }
    ((usvec4*)dst)[i] = o;
  }
}

// ============ 256x256 8-phase bf16 NT GEMM (C = A * Bw^T), BK=64 ============
// K-loop identical to rounds 3-5 (8 waves 2Mx4N, wave tile 128x64, 2-buf LDS,
// counted vmcnt(4), both-sides k16^row&7 swizzle). Round-6 change: epilogue
// stores are LDS-transposed to FULL-LINE wide stores (f32x4 / 16B bf16 chunks)
// to kill L2 write-allocate fetches (round-5 FETCH ~= ideal + WRITE).

template <int MODE>
__global__ __launch_bounds__(512, 2)
void mla_gemm(const __hip_bfloat16* __restrict__ A0p,
              const __hip_bfloat16* __restrict__ B0p, int K0,
              const __hip_bfloat16* __restrict__ A1p,
              const __hip_bfloat16* __restrict__ B1p,
              unsigned short* __restrict__ qlora,
              const float* __restrict__ cosp,
              const float* __restrict__ sinp,
              float* __restrict__ out) {
  extern __shared__ __align__(128) char lds[];
  const int tid = threadIdx.x;
  const int lane = tid & 63;
  const int w = tid >> 6;
  const int wm = w >> 2, wn = w & 3;
  const int l15 = lane & 15, lhi = lane >> 4;
  const int srow8 = lane >> 3;
  const int swzc = ((lane & 7) ^ srow8) * 8;   // swizzled source chunk (elements)

  const __hip_bfloat16* Aptr;
  const __hip_bfloat16* Bptr;
  int K, bm, bn;
  bool isA2 = false;
  if constexpr (MODE == 0) {
    const int swz = ((int)blockIdx.x & 7) * 32 + ((int)blockIdx.x >> 3);
    bm = swz >> 3; bn = swz & 7;
    Aptr = A0p; Bptr = B0p; K = K0;
  } else {
    const int bid = (int)blockIdx.x;
    if (bid < 32) {  // k_pe slice: x @ w1 cols 2048.. (K=4096)
      isA2 = true; bm = bid; bn = 8; Aptr = A1p; Bptr = B1p; K = 4096;
    } else {
      const int b2 = bid - 32;
      const int swz = (b2 & 7) * 96 + (b2 >> 3);
      bm = swz / 24; bn = swz - bm * 24;
      Aptr = A0p; Bptr = B0p; K = K0;
    }
  }
  const long brow = (long)bm * 256;
  const int bcol = bn * 256;

  const __hip_bfloat16* aSt = Aptr + (brow + w * 16 + srow8) * (long)K + swzc;
  const __hip_bfloat16* bSt = Bptr + ((long)bcol + srow8) * (long)K + swzc;
  const int wj0 = w * 16, wj1 = w * 16 + 8;
  const int cb_j0 = (2 * (wj0 >> 5)) * 32 + (wj0 & 31);
  const int cb_j1 = (2 * (wj1 >> 5)) * 32 + (wj1 & 31);
  const int ldsWj = w * 2048;

  const int aRdRow = (wm * 64 + l15) * 128;
  const int bRdRow = (wn * 32 + l15) * 128;
  const int ck0 = (lhi ^ (l15 & 7)) * 16;

  f32x4 acc[8][4] = {};
  bf16x8 aF[4][2];
  bf16x8 bF[2][2][2];

  const int T = K >> 6;
  const int I = T >> 1;

  auto stage = [&](int u, int kt) {
    const int b = kt & 1;
    if (u < 2) {
      const int off = b * 32768 + u * 16384 + ldsWj;
      __builtin_amdgcn_global_load_lds((AS1 void*)(aSt + (long)(u * 128) * K + kt * 64),
                                       (AS3 void*)(lds + off), 16, 0, 0);
      __builtin_amdgcn_global_load_lds((AS1 void*)(aSt + (long)(u * 128 + 8) * K + kt * 64),
                                       (AS3 void*)(lds + off + 1024), 16, 0, 0);
    } else {
      const int h = u - 2;
      const int off = 65536 + b * 32768 + h * 16384 + ldsWj;
      __builtin_amdgcn_global_load_lds((AS1 void*)(bSt + (long)(cb_j0 + h * 32) * K + kt * 64),
                                       (AS3 void*)(lds + off), 16, 0, 0);
      __builtin_amdgcn_global_load_lds((AS1 void*)(bSt + (long)(cb_j1 + h * 32) * K + kt * 64),
                                       (AS3 void*)(lds + off + 1024), 16, 0, 0);
    }
  };
  auto readA = [&](int qh, int b) {
    const int base = b * 32768 + qh * 16384 + aRdRow;
    #pragma unroll
    for (int fr = 0; fr < 4; ++fr) {
      aF[fr][0] = *(const bf16x8*)(lds + base + fr * 2048 + ck0);
      aF[fr][1] = *(const bf16x8*)(lds + base + fr * 2048 + (ck0 ^ 64));
    }
  };
  auto readB = [&](int c, int b) {
    const int base = 65536 + b * 32768 + c * 16384 + bRdRow;
    #pragma unroll
    for (int fq = 0; fq < 2; ++fq) {
      bF[c][fq][0] = *(const bf16x8*)(lds + base + fq * 2048 + ck0);
      bF[c][fq][1] = *(const bf16x8*)(lds + base + fq * 2048 + (ck0 ^ 64));
    }
  };
  auto mmac = [&](int qh, int c) {
    __builtin_amdgcn_s_setprio(1);
    #pragma unroll
    for (int fr = 0; fr < 4; ++fr)
      #pragma unroll
      for (int fq = 0; fq < 2; ++fq) {
        acc[qh * 4 + fr][c * 2 + fq] = __builtin_amdgcn_mfma_f32_16x16x32_bf16(
            aF[fr][0], bF[c][fq][0], acc[qh * 4 + fr][c * 2 + fq], 0, 0, 0);
        acc[qh * 4 + fr][c * 2 + fq] = __builtin_amdgcn_mfma_f32_16x16x32_bf16(
            aF[fr][1], bF[c][fq][1], acc[qh * 4 + fr][c * 2 + fq], 0, 0, 0);
      }
    __builtin_amdgcn_s_setprio(0);
  };
  #define BAR() __builtin_amdgcn_s_barrier()
  #define LGKM0() do { asm volatile("s_waitcnt lgkmcnt(0)" ::: "memory"); \
                       __builtin_amdgcn_sched_barrier(0); } while (0)

  stage(0, 0); stage(1, 0); stage(2, 0); stage(3, 0);
  stage(0, 1); stage(3, 1);
  asm volatile("s_waitcnt vmcnt(4)" ::: "memory");
  BAR();

  for (int i = 0; i < I; ++i) {
    const int ktB = 2 * i + 1;
    const bool more = (i < I - 1);
    readA(0, 0); readB(0, 0); stage(1, ktB);
    BAR(); LGKM0(); mmac(0, 0); BAR();
    readB(1, 0); stage(2, ktB);
    BAR(); LGKM0(); mmac(0, 1); BAR();
    readA(1, 0); if (more) stage(0, ktB + 1);
    BAR(); LGKM0(); mmac(1, 1); BAR();
    if (more) stage(3, ktB + 1);
    BAR(); LGKM0(); mmac(1, 0);
    if (more) asm volatile("s_waitcnt vmcnt(4)" ::: "memory");
    else      asm volatile("s_waitcnt vmcnt(0)" ::: "memory");
    BAR();
    readA(0, 1); readB(0, 1); if (more) stage(1, ktB + 1);
    BAR(); LGKM0(); mmac(0, 0); BAR();
    readB(1, 1); if (more) stage(2, ktB + 1);
    BAR(); LGKM0(); mmac(0, 1); BAR();
    readA(1, 1); if (more) stage(0, ktB + 2);
    BAR(); LGKM0(); mmac(1, 1); BAR();
    if (more) stage(3, ktB + 2);
    BAR(); LGKM0(); mmac(1, 0);
    if (more) asm volatile("s_waitcnt vmcnt(4)" ::: "memory");
    else      asm volatile("s_waitcnt vmcnt(0)" ::: "memory");
    BAR();
  }

  // ---- epilogue: LDS-transposed FULL-LINE stores ----
  // acc value (i8,j,r) is at row = brow + (i8>>2)*128 + wm*64 + (i8&3)*16 + lhi*4 + r,
  //                       col = bcol + wn*64 + (j>>1)*32 + (j&1)*16 + l15.
  // Per i8 the wave owns a 16x64 tile; stage to LDS, re-read so each lane holds
  // 16B of ONE row, store wide: 64 lanes cover 4 rows x 256B contiguous.
  // After the final barrier no wave reads the K-loop LDS; each wave uses its own
  // 4KB at w*4096 (wave-local => lgkmcnt(0) only, no barriers).
  const int wcol = bcol + wn * 64;
  const long rbase = brow + wm * 64;
  char* eplds = lds + w * 4096;

  auto storeTileF32 = [&](int i8, float* dst, bool rope) {
    #pragma unroll
    for (int j = 0; j < 4; ++j)
      #pragma unroll
      for (int r = 0; r < 4; ++r) {
        float v = acc[i8][j][r];
        if (rope) {
          const long row = rbase + (i8 >> 2) * 128 + (i8 & 3) * 16 + lhi * 4 + r;
          const int d = (j >> 1) * 32 + (j & 1) * 16 + l15;
          const float rot = (j < 2) ? -acc[i8][j + 2][r] : acc[i8][j - 2][r];
          v = v * cosp[row * 64 + d] + rot * sinp[row * 64 + d];
        }
        *(float*)(eplds + (lhi * 4 + r) * 256 + ((j >> 1) * 32 + (j & 1) * 16 + l15) * 4) = v;
      }
    asm volatile("s_waitcnt lgkmcnt(0)" ::: "memory");
    #pragma unroll
    for (int t = 0; t < 4; ++t) {
      const int r16 = t * 4 + (lane >> 4);
      const f32x4 v = *(const f32x4*)(eplds + r16 * 256 + (lane & 15) * 16);
      const long row = rbase + (i8 >> 2) * 128 + (i8 & 3) * 16 + r16;
      __builtin_nontemporal_store(v, (f32x4*)(dst + row * 6720 + (lane & 15) * 4));
    }
  };
  auto storeTileBf16 = [&](int i8) {
    #pragma unroll
    for (int j = 0; j < 4; ++j)
      #pragma unroll
      for (int r = 0; r < 4; ++r)
        *(unsigned short*)(eplds + (lhi * 4 + r) * 128 +
                           ((j >> 1) * 32 + (j & 1) * 16 + l15) * 2) = f2bf(acc[i8][j][r]);
    asm volatile("s_waitcnt lgkmcnt(0)" ::: "memory");
    #pragma unroll
    for (int t = 0; t < 2; ++t) {
      const int r16 = t * 8 + (lane >> 3);
      const ui32x4 v = *(const ui32x4*)(eplds + r16 * 128 + (lane & 7) * 16);
      const long row = rbase + (i8 >> 2) * 128 + (i8 & 3) * 16 + r16;
      *(ui32x4*)((char*)qlora + (row * 1536 + wcol) * 2 + (lane & 7) * 16) = v;
    }
  };

  if constexpr (MODE == 0) {
    if (wcol < 1536) {          // q_lora bf16 (cached; re-read by launch2)
      #pragma unroll
      for (int i8 = 0; i8 < 8; ++i8) storeTileBf16(i8);
    } else {                    // compressed_kv -> out cols 6208..6719
      #pragma unroll
      for (int i8 = 0; i8 < 8; ++i8) storeTileF32(i8, out + wcol + 4672, false);
    }
  } else {
    if (isA2) {
      if (wn == 0) {            // k_pe + RoPE -> out cols 6144..6207
        #pragma unroll
        for (int i8 = 0; i8 < 8; ++i8) storeTileF32(i8, out + 6144, true);
      }                         // wn 1..3: pad cols, dropped
    } else if ((wcol % 192) != 128) {  // q_nope
      #pragma unroll
      for (int i8 = 0; i8 < 8; ++i8) storeTileF32(i8, out + wcol, false);
    } else {                    // q_pe 64-block + RoPE
      #pragma unroll
      for (int i8 = 0; i8 < 8; ++i8) storeTileF32(i8, out + wcol, true);
    }
  }
  #undef BAR
  #undef LGKM0
}

// ---------------- launch ----------------

extern "C" void kernel_launch(void* const* d_in, const int* in_sizes, int n_in,
                              void* d_out, int out_size, void* d_ws, size_t ws_size,
                              hipStream_t stream) {
  const float* x    = (const float*)d_in[0];
  const float* cosp = (const float*)d_in[1];
  const float* sinp = (const float*)d_in[2];
  const float* Wqa  = (const float*)d_in[3];
  const float* Wqb  = (const float*)d_in[4];
  const float* Wkva = (const float*)d_in[5];
  float* out = (float*)d_out;

  char* ws = (char*)d_ws;
  __hip_bfloat16* xb  = (__hip_bfloat16*)ws;
  __hip_bfloat16* w1  = (__hip_bfloat16*)(ws + 67108864L);
  __hip_bfloat16* wqb = (__hip_bfloat16*)(ws + 67108864L + 17825792L);
  unsigned short* ql  = (unsigned short*)(ws + 67108864L + 17825792L + 18874368L);

  cvt_bf16_kernel<<<2048, 256, 0, stream>>>(x,   (unsigned short*)xb,  8192L * 4096 / 4);
  cvt_bf16_kernel<<<1024, 256, 0, stream>>>(Wqa, (unsigned short*)w1,  1536L * 4096 / 4);
  cvt_pad_kernel<<<640, 256, 0, stream>>>(Wkva, (unsigned short*)(w1 + 1536L * 4096),
                                          576L * 4096 / 4, 640L * 4096 / 4);
  cvt_bf16_kernel<<<1024, 256, 0, stream>>>(Wqb, (unsigned short*)wqb, 6144L * 1536 / 4);

  (void)hipFuncSetAttribute((const void*)&mla_gemm<0>,
                            hipFuncAttributeMaxDynamicSharedMemorySize, 131072);
  (void)hipFuncSetAttribute((const void*)&mla_gemm<1>,
                            hipFuncAttributeMaxDynamicSharedMemorySize, 131072);

  // launch1: x @ w1[0:2048] -> q_lora + compressed_kv. 256 blocks (1 round).
  mla_gemm<0><<<dim3(256), 512, 131072, stream>>>(xb, w1, 4096, nullptr, nullptr,
                                                  ql, cosp, sinp, out);
  // launch2: 32 k_pe blocks (K=4096, dispatched first = LPT) + 768 q blocks (K=1536).
  mla_gemm<1><<<dim3(800), 512, 131072, stream>>>((const __hip_bfloat16*)ql, wqb, 1536,
                                                  xb, w1, ql, cosp, sinp, out);
}

// Round 7
// 358.442 us; speedup vs baseline: 1.1715x; 1.0116x over previous
//
#include <hip/hip_runtime.h>
#include <hip/hip_bf16.h>
#include <stdint.h>

typedef __bf16 bf16x8 __attribute__((ext_vector_type(8)));
typedef float f32x4 __attribute__((ext_vector_type(4)));
typedef float fvec4 __attribute__((ext_vector_type(4)));
typedef unsigned short usvec4 __attribute__((ext_vector_type(4)));
typedef unsigned int ui32x4 __attribute__((ext_vector_type(4)));

#define AS3 __attribute__((address_space(3)))
#define AS1 __attribute__((address_space(1)))

static __device__ __forceinline__ unsigned short f2bf(float f) {
  unsigned int u = __float_as_uint(f);
  u += 0x7FFF + ((u >> 16) & 1);   // round-to-nearest-even
  return (unsigned short)(u >> 16);
}

// ---------------- fp32 -> bf16 conversion kernels ----------------

extern "C" __global__ void cvt_bf16_kernel(const float* __restrict__ src,
                                           unsigned short* __restrict__ dst,
                                           long n4) {
  long i = (long)blockIdx.x * blockDim.x + threadIdx.x;
  const long stride = (long)gridDim.x * blockDim.x;
  for (; i < n4; i += stride) {
    const fvec4 v = __builtin_nontemporal_load(&((const fvec4*)src)[i]);
    usvec4 o;
    o.x = f2bf(v.x); o.y = f2bf(v.y); o.z = f2bf(v.z); o.w = f2bf(v.w);
    ((usvec4*)dst)[i] = o;
  }
}

extern "C" __global__ void cvt_pad_kernel(const float* __restrict__ src,
                                          unsigned short* __restrict__ dst,
                                          long nsrc4, long ntot4) {
  long i = (long)blockIdx.x * blockDim.x + threadIdx.x;
  const long stride = (long)gridDim.x * blockDim.x;
  for (; i < ntot4; i += stride) {
    usvec4 o = {0, 0, 0, 0};
    if (i < nsrc4) {
      const fvec4 v = __builtin_nontemporal_load(&((const fvec4*)src)[i]);
      o.x = f2bf(v.x); o.y = f2bf(v.y); o.z = f2bf(v.z); o.w = f2bf(v.w);
    }
    ((usvec4*)dst)[i] = o;
  }
}

// ============ 256x256 8-phase bf16 NT GEMM (C = A * Bw^T), BK=64 ============
// Round-7 change: UNIFORM LEAD-7 staging schedule. Rule: stage of half-tile X
// of tile t may issue in any phase strictly after the last read of X(t-2)
// (phase barriers guarantee all waves' reads done). Assignments per iter i
// (tiles e2=2i+2 -> buf0, o2=2i+3 -> buf1):
//   p1: A0,B0(e2)  p2: B1(e2)  p3: A1(e2)  |  p5: A0,B0(o2)  p6: B1(o2)  p7: A1(o2)
// Every half-tile: issue->consume lead = 7 phases (~1000 cyc) covering HBM miss.
// Counted per-phase waits (issue counts 0/4/2/2 per quadrant):
//   steady: end-p0/p4: vmcnt(10); end-p1/p5: vmcnt(12); end-p3/p7: vmcnt(12)
//   peeled tail iter (no stages): 10, 8, -, 4, 2, 0, -, -
// Prologue: tiles 0,1 in order {A0,B0,B1,A1} x2 (16 issues), vmcnt(12), barrier.
// Epilogue (round 6): LDS-transposed full-line wide stores.

#define VMW(N) asm volatile("s_waitcnt vmcnt(" #N ")" ::: "memory")
#define BAR() __builtin_amdgcn_s_barrier()
#define LGKM0() do { asm volatile("s_waitcnt lgkmcnt(0)" ::: "memory"); \
                     __builtin_amdgcn_sched_barrier(0); } while (0)

template <int MODE>
__global__ __launch_bounds__(512, 2)
void mla_gemm(const __hip_bfloat16* __restrict__ A0p,
              const __hip_bfloat16* __restrict__ B0p, int K0,
              const __hip_bfloat16* __restrict__ A1p,
              const __hip_bfloat16* __restrict__ B1p,
              unsigned short* __restrict__ qlora,
              const float* __restrict__ cosp,
              const float* __restrict__ sinp,
              float* __restrict__ out) {
  extern __shared__ __align__(128) char lds[];
  const int tid = threadIdx.x;
  const int lane = tid & 63;
  const int w = tid >> 6;
  const int wm = w >> 2, wn = w & 3;
  const int l15 = lane & 15, lhi = lane >> 4;
  const int srow8 = lane >> 3;
  const int swzc = ((lane & 7) ^ srow8) * 8;   // swizzled source chunk (elements)

  const __hip_bfloat16* Aptr;
  const __hip_bfloat16* Bptr;
  int K, bm, bn;
  bool isA2 = false;
  if constexpr (MODE == 0) {
    const int swz = ((int)blockIdx.x & 7) * 32 + ((int)blockIdx.x >> 3);
    bm = swz >> 3; bn = swz & 7;
    Aptr = A0p; Bptr = B0p; K = K0;
  } else {
    const int bid = (int)blockIdx.x;
    if (bid < 32) {  // k_pe slice: x @ w1 cols 2048.. (K=4096)
      isA2 = true; bm = bid; bn = 8; Aptr = A1p; Bptr = B1p; K = 4096;
    } else {
      const int b2 = bid - 32;
      const int swz = (b2 & 7) * 96 + (b2 >> 3);
      bm = swz / 24; bn = swz - bm * 24;
      Aptr = A0p; Bptr = B0p; K = K0;
    }
  }
  const long brow = (long)bm * 256;
  const int bcol = bn * 256;

  const __hip_bfloat16* aSt = Aptr + (brow + w * 16 + srow8) * (long)K + swzc;
  const __hip_bfloat16* bSt = Bptr + ((long)bcol + srow8) * (long)K + swzc;
  const int wj0 = w * 16, wj1 = w * 16 + 8;
  const int cb_j0 = (2 * (wj0 >> 5)) * 32 + (wj0 & 31);
  const int cb_j1 = (2 * (wj1 >> 5)) * 32 + (wj1 & 31);
  const int ldsWj = w * 2048;

  const int aRdRow = (wm * 64 + l15) * 128;
  const int bRdRow = (wn * 32 + l15) * 128;
  const int ck0 = (lhi ^ (l15 & 7)) * 16;

  f32x4 acc[8][4] = {};
  bf16x8 aF[4][2];
  bf16x8 bF[2][2][2];

  const int T = K >> 6;
  const int I = T >> 1;

  // u: 0=A half0, 1=A half1, 2=B half0, 3=B half1
  auto stage = [&](int u, int kt) {
    const int b = kt & 1;
    if (u < 2) {
      const int off = b * 32768 + u * 16384 + ldsWj;
      __builtin_amdgcn_global_load_lds((AS1 void*)(aSt + (long)(u * 128) * K + kt * 64),
                                       (AS3 void*)(lds + off), 16, 0, 0);
      __builtin_amdgcn_global_load_lds((AS1 void*)(aSt + (long)(u * 128 + 8) * K + kt * 64),
                                       (AS3 void*)(lds + off + 1024), 16, 0, 0);
    } else {
      const int h = u - 2;
      const int off = 65536 + b * 32768 + h * 16384 + ldsWj;
      __builtin_amdgcn_global_load_lds((AS1 void*)(bSt + (long)(cb_j0 + h * 32) * K + kt * 64),
                                       (AS3 void*)(lds + off), 16, 0, 0);
      __builtin_amdgcn_global_load_lds((AS1 void*)(bSt + (long)(cb_j1 + h * 32) * K + kt * 64),
                                       (AS3 void*)(lds + off + 1024), 16, 0, 0);
    }
  };
  auto readA = [&](int qh, int b) {
    const int base = b * 32768 + qh * 16384 + aRdRow;
    #pragma unroll
    for (int fr = 0; fr < 4; ++fr) {
      aF[fr][0] = *(const bf16x8*)(lds + base + fr * 2048 + ck0);
      aF[fr][1] = *(const bf16x8*)(lds + base + fr * 2048 + (ck0 ^ 64));
    }
  };
  auto readB = [&](int c, int b) {
    const int base = 65536 + b * 32768 + c * 16384 + bRdRow;
    #pragma unroll
    for (int fq = 0; fq < 2; ++fq) {
      bF[c][fq][0] = *(const bf16x8*)(lds + base + fq * 2048 + ck0);
      bF[c][fq][1] = *(const bf16x8*)(lds + base + fq * 2048 + (ck0 ^ 64));
    }
  };
  auto mmac = [&](int qh, int c) {
    __builtin_amdgcn_s_setprio(1);
    #pragma unroll
    for (int fr = 0; fr < 4; ++fr)
      #pragma unroll
      for (int fq = 0; fq < 2; ++fq) {
        acc[qh * 4 + fr][c * 2 + fq] = __builtin_amdgcn_mfma_f32_16x16x32_bf16(
            aF[fr][0], bF[c][fq][0], acc[qh * 4 + fr][c * 2 + fq], 0, 0, 0);
        acc[qh * 4 + fr][c * 2 + fq] = __builtin_amdgcn_mfma_f32_16x16x32_bf16(
            aF[fr][1], bF[c][fq][1], acc[qh * 4 + fr][c * 2 + fq], 0, 0, 0);
      }
    __builtin_amdgcn_s_setprio(0);
  };

  // prologue: tiles 0,1 each in order {A0, B0, B1, A1}; wait -> tile0 A0,B0 landed
  stage(0, 0); stage(2, 0); stage(3, 0); stage(1, 0);
  stage(0, 1); stage(2, 1); stage(3, 1); stage(1, 1);
  VMW(12);
  BAR();

  for (int i = 0; i < I - 1; ++i) {
    const int e2 = 2 * i + 2, o2 = 2 * i + 3;
    // p0
    readA(0, 0); readB(0, 0);
    BAR(); LGKM0(); mmac(0, 0); VMW(10); BAR();
    // p1
    readB(1, 0); stage(0, e2); stage(2, e2);
    BAR(); LGKM0(); mmac(0, 1); VMW(12); BAR();
    // p2
    readA(1, 0); stage(3, e2);
    BAR(); LGKM0(); mmac(1, 1); BAR();
    // p3
    stage(1, e2);
    BAR(); LGKM0(); mmac(1, 0); VMW(12); BAR();
    // p4
    readA(0, 1); readB(0, 1);
    BAR(); LGKM0(); mmac(0, 0); VMW(10); BAR();
    // p5
    readB(1, 1); stage(0, o2); stage(2, o2);
    BAR(); LGKM0(); mmac(0, 1); VMW(12); BAR();
    // p6
    readA(1, 1); stage(3, o2);
    BAR(); LGKM0(); mmac(1, 1); BAR();
    // p7
    stage(1, o2);
    BAR(); LGKM0(); mmac(1, 0); VMW(12); BAR();
  }
  // peeled tail iteration (no stages; drain counts)
  readA(0, 0); readB(0, 0);
  BAR(); LGKM0(); mmac(0, 0); VMW(10); BAR();
  readB(1, 0);
  BAR(); LGKM0(); mmac(0, 1); VMW(8); BAR();
  readA(1, 0);
  BAR(); LGKM0(); mmac(1, 1); BAR();
  BAR(); LGKM0(); mmac(1, 0); VMW(4); BAR();
  readA(0, 1); readB(0, 1);
  BAR(); LGKM0(); mmac(0, 0); VMW(2); BAR();
  readB(1, 1);
  BAR(); LGKM0(); mmac(0, 1); VMW(0); BAR();
  readA(1, 1);
  BAR(); LGKM0(); mmac(1, 1); BAR();
  BAR(); LGKM0(); mmac(1, 0); BAR();

  // ---- epilogue: LDS-transposed FULL-LINE stores ----
  // acc value (i8,j,r): row = brow + (i8>>2)*128 + wm*64 + (i8&3)*16 + lhi*4 + r,
  //                     col = bcol + wn*64 + (j>>1)*32 + (j&1)*16 + l15.
  // Each wave transposes its 16x64 tile through its own 4KB LDS (wave-local,
  // lgkmcnt(0) only), then stores f32x4 per lane: 4 rows x 256B full lines.
  const int wcol = bcol + wn * 64;
  const long rbase = brow + wm * 64;
  char* eplds = lds + w * 4096;

  auto storeTileF32 = [&](int i8, float* dst, bool rope) {
    #pragma unroll
    for (int j = 0; j < 4; ++j)
      #pragma unroll
      for (int r = 0; r < 4; ++r) {
        float v = acc[i8][j][r];
        if (rope) {
          const long row = rbase + (i8 >> 2) * 128 + (i8 & 3) * 16 + lhi * 4 + r;
          const int d = (j >> 1) * 32 + (j & 1) * 16 + l15;
          const float rot = (j < 2) ? -acc[i8][j + 2][r] : acc[i8][j - 2][r];
          v = v * cosp[row * 64 + d] + rot * sinp[row * 64 + d];
        }
        *(float*)(eplds + (lhi * 4 + r) * 256 + ((j >> 1) * 32 + (j & 1) * 16 + l15) * 4) = v;
      }
    asm volatile("s_waitcnt lgkmcnt(0)" ::: "memory");
    #pragma unroll
    for (int t = 0; t < 4; ++t) {
      const int r16 = t * 4 + (lane >> 4);
      const f32x4 v = *(const f32x4*)(eplds + r16 * 256 + (lane & 15) * 16);
      const long row = rbase + (i8 >> 2) * 128 + (i8 & 3) * 16 + r16;
      __builtin_nontemporal_store(v, (f32x4*)(dst + row * 6720 + (lane & 15) * 4));
    }
  };
  auto storeTileBf16 = [&](int i8) {
    #pragma unroll
    for (int j = 0; j < 4; ++j)
      #pragma unroll
      for (int r = 0; r < 4; ++r)
        *(unsigned short*)(eplds + (lhi * 4 + r) * 128 +
                           ((j >> 1) * 32 + (j & 1) * 16 + l15) * 2) = f2bf(acc[i8][j][r]);
    asm volatile("s_waitcnt lgkmcnt(0)" ::: "memory");
    #pragma unroll
    for (int t = 0; t < 2; ++t) {
      const int r16 = t * 8 + (lane >> 3);
      const ui32x4 v = *(const ui32x4*)(eplds + r16 * 128 + (lane & 7) * 16);
      const long row = rbase + (i8 >> 2) * 128 + (i8 & 3) * 16 + r16;
      *(ui32x4*)((char*)qlora + (row * 1536 + wcol) * 2 + (lane & 7) * 16) = v;
    }
  };

  if constexpr (MODE == 0) {
    if (wcol < 1536) {          // q_lora bf16 (cached; re-read by launch2)
      #pragma unroll
      for (int i8 = 0; i8 < 8; ++i8) storeTileBf16(i8);
    } else {                    // compressed_kv -> out cols 6208..6719
      #pragma unroll
      for (int i8 = 0; i8 < 8; ++i8) storeTileF32(i8, out + wcol + 4672, false);
    }
  } else {
    if (isA2) {
      if (wn == 0) {            // k_pe + RoPE -> out cols 6144..6207
        #pragma unroll
        for (int i8 = 0; i8 < 8; ++i8) storeTileF32(i8, out + 6144, true);
      }                         // wn 1..3: pad cols, dropped
    } else if ((wcol % 192) != 128) {  // q_nope
      #pragma unroll
      for (int i8 = 0; i8 < 8; ++i8) storeTileF32(i8, out + wcol, false);
    } else {                    // q_pe 64-block + RoPE
      #pragma unroll
      for (int i8 = 0; i8 < 8; ++i8) storeTileF32(i8, out + wcol, true);
    }
  }
}

// ---------------- launch ----------------

extern "C" void kernel_launch(void* const* d_in, const int* in_sizes, int n_in,
                              void* d_out, int out_size, void* d_ws, size_t ws_size,
                              hipStream_t stream) {
  const float* x    = (const float*)d_in[0];
  const float* cosp = (const float*)d_in[1];
  const float* sinp = (const float*)d_in[2];
  const float* Wqa  = (const float*)d_in[3];
  const float* Wqb  = (const float*)d_in[4];
  const float* Wkva = (const float*)d_in[5];
  float* out = (float*)d_out;

  char* ws = (char*)d_ws;
  __hip_bfloat16* xb  = (__hip_bfloat16*)ws;
  __hip_bfloat16* w1  = (__hip_bfloat16*)(ws + 67108864L);
  __hip_bfloat16* wqb = (__hip_bfloat16*)(ws + 67108864L + 17825792L);
  unsigned short* ql  = (unsigned short*)(ws + 67108864L + 17825792L + 18874368L);

  cvt_bf16_kernel<<<2048, 256, 0, stream>>>(x,   (unsigned short*)xb,  8192L * 4096 / 4);
  cvt_bf16_kernel<<<1024, 256, 0, stream>>>(Wqa, (unsigned short*)w1,  1536L * 4096 / 4);
  cvt_pad_kernel<<<640, 256, 0, stream>>>(Wkva, (unsigned short*)(w1 + 1536L * 4096),
                                          576L * 4096 / 4, 640L * 4096 / 4);
  cvt_bf16_kernel<<<1024, 256, 0, stream>>>(Wqb, (unsigned short*)wqb, 6144L * 1536 / 4);

  (void)hipFuncSetAttribute((const void*)&mla_gemm<0>,
                            hipFuncAttributeMaxDynamicSharedMemorySize, 131072);
  (void)hipFuncSetAttribute((const void*)&mla_gemm<1>,
                            hipFuncAttributeMaxDynamicSharedMemorySize, 131072);

  // launch1: x @ w1[0:2048] -> q_lora + compressed_kv. 256 blocks (1 round).
  mla_gemm<0><<<dim3(256), 512, 131072, stream>>>(xb, w1, 4096, nullptr, nullptr,
                                                  ql, cosp, sinp, out);
  // launch2: 32 k_pe blocks (K=4096, dispatched first = LPT) + 768 q blocks (K=1536).
  mla_gemm<1><<<dim3(800), 512, 131072, stream>>>((const __hip_bfloat16*)ql, wqb, 1536,
                                                  xb, w1, ql, cosp, sinp, out);
}

// Round 8
// 341.546 us; speedup vs baseline: 1.2294x; 1.0495x over previous
//
#include <hip/hip_runtime.h>
#include <hip/hip_bf16.h>
#include <stdint.h>

typedef __bf16 bf16x8 __attribute__((ext_vector_type(8)));
typedef float f32x4 __attribute__((ext_vector_type(4)));
typedef float fvec4 __attribute__((ext_vector_type(4)));
typedef unsigned short usvec4 __attribute__((ext_vector_type(4)));
typedef unsigned int ui32x4 __attribute__((ext_vector_type(4)));

#define AS3 __attribute__((address_space(3)))
#define AS1 __attribute__((address_space(1)))

static __device__ __forceinline__ unsigned short f2bf(float f) {
  unsigned int u = __float_as_uint(f);
  u += 0x7FFF + ((u >> 16) & 1);   // round-to-nearest-even
  return (unsigned short)(u >> 16);
}

// ---------------- fp32 -> bf16 conversion kernels ----------------

extern "C" __global__ void cvt_bf16_kernel(const float* __restrict__ src,
                                           unsigned short* __restrict__ dst,
                                           long n4) {
  long i = (long)blockIdx.x * blockDim.x + threadIdx.x;
  const long stride = (long)gridDim.x * blockDim.x;
  for (; i < n4; i += stride) {
    const fvec4 v = __builtin_nontemporal_load(&((const fvec4*)src)[i]);
    usvec4 o;
    o.x = f2bf(v.x); o.y = f2bf(v.y); o.z = f2bf(v.z); o.w = f2bf(v.w);
    ((usvec4*)dst)[i] = o;
  }
}

extern "C" __global__ void cvt_pad_kernel(const float* __restrict__ src,
                                          unsigned short* __restrict__ dst,
                                          long nsrc4, long ntot4) {
  long i = (long)blockIdx.x * blockDim.x + threadIdx.x;
  const long stride = (long)gridDim.x * blockDim.x;
  for (; i < ntot4; i += stride) {
    usvec4 o = {0, 0, 0, 0};
    if (i < nsrc4) {
      const fvec4 v = __builtin_nontemporal_load(&((const fvec4*)src)[i]);
      o.x = f2bf(v.x); o.y = f2bf(v.y); o.z = f2bf(v.z); o.w = f2bf(v.w);
    }
    ((usvec4*)dst)[i] = o;
  }
}

// ============ 256x256 bf16 NT GEMM (C = A * Bw^T), BK=64 ============
// Round-8 change: ONE barrier per phase (4/tile instead of 8). Phase block:
//   { ds_reads(q); gload stages; [VMW(n)]; s_barrier; sched_barrier(0);
//     [lgkmcnt(0)+sched_barrier(0)]; 16 MFMA }
// Overwrite safety: a stage issued in phase p is safe to write region R iff
// R's last ds_reads were in phase <= p-2 (each wave's lgkmcnt(0) for phase
// p-2 precedes the barrier of phase p-1, which precedes the stage issue).
// Schedule (tile t, buf b=t&1): q0 reads A0,B0 -> mmac(0,0); q1 reads B1 ->
// mmac(0,1); q2 reads A1 -> mmac(1,1); q3 (regs only) -> mmac(1,0).
// Stages: q0: A1(t+1) [last read q2(t-1), gap 2]; q2: A0,B0(t+2) [q0(t), gap 2];
//         q3: B1(t+2) [q1(t), gap 2].
// Counted vmcnt (2 gloads per stage call; 8 issued per tile):
//   steady: VMW(10)@q0 (guards B1(t) for q1 reads), VMW(8)@q1 (guards A1(t)),
//           VMW(10)@q3 (guards A0B0(t+1) for next q0 reads).
//   peel t=T-2: VMW(4)@q3; t=T-1: VMW(2)@q0, VMW(0)@q1.
// Swizzle: both-sides k16-chunk ^ row&7 (bank-conflict-free, LDS dest linear).
// Epilogue: LDS-transposed full-line wide stores (round 6).

#define VMW(N) asm volatile("s_waitcnt vmcnt(" #N ")" ::: "memory")
#define BAR() do { __builtin_amdgcn_s_barrier(); \
                   __builtin_amdgcn_sched_barrier(0); } while (0)
#define LGKM0() do { asm volatile("s_waitcnt lgkmcnt(0)" ::: "memory"); \
                     __builtin_amdgcn_sched_barrier(0); } while (0)

template <int MODE>
__global__ __launch_bounds__(512, 2)
void mla_gemm(const __hip_bfloat16* __restrict__ A0p,
              const __hip_bfloat16* __restrict__ B0p, int K0,
              const __hip_bfloat16* __restrict__ A1p,
              const __hip_bfloat16* __restrict__ B1p,
              unsigned short* __restrict__ qlora,
              const float* __restrict__ cosp,
              const float* __restrict__ sinp,
              float* __restrict__ out) {
  extern __shared__ __align__(128) char lds[];
  const int tid = threadIdx.x;
  const int lane = tid & 63;
  const int w = tid >> 6;
  const int wm = w >> 2, wn = w & 3;
  const int l15 = lane & 15, lhi = lane >> 4;
  const int srow8 = lane >> 3;
  const int swzc = ((lane & 7) ^ srow8) * 8;   // swizzled source chunk (elements)

  const __hip_bfloat16* Aptr;
  const __hip_bfloat16* Bptr;
  int K, bm, bn;
  bool isA2 = false;
  if constexpr (MODE == 0) {
    const int swz = ((int)blockIdx.x & 7) * 32 + ((int)blockIdx.x >> 3);
    bm = swz >> 3; bn = swz & 7;
    Aptr = A0p; Bptr = B0p; K = K0;
  } else {
    const int bid = (int)blockIdx.x;
    if (bid < 32) {  // k_pe slice: x @ w1 cols 2048.. (K=4096)
      isA2 = true; bm = bid; bn = 8; Aptr = A1p; Bptr = B1p; K = 4096;
    } else {
      const int b2 = bid - 32;
      const int swz = (b2 & 7) * 96 + (b2 >> 3);
      bm = swz / 24; bn = swz - bm * 24;
      Aptr = A0p; Bptr = B0p; K = K0;
    }
  }
  const long brow = (long)bm * 256;
  const int bcol = bn * 256;

  const __hip_bfloat16* aSt = Aptr + (brow + w * 16 + srow8) * (long)K + swzc;
  const __hip_bfloat16* bSt = Bptr + ((long)bcol + srow8) * (long)K + swzc;
  const int wj0 = w * 16, wj1 = w * 16 + 8;
  const int cb_j0 = (2 * (wj0 >> 5)) * 32 + (wj0 & 31);
  const int cb_j1 = (2 * (wj1 >> 5)) * 32 + (wj1 & 31);
  const int ldsWj = w * 2048;

  const int aRdRow = (wm * 64 + l15) * 128;
  const int bRdRow = (wn * 32 + l15) * 128;
  const int ck0 = (lhi ^ (l15 & 7)) * 16;

  f32x4 acc[8][4] = {};
  bf16x8 aF[4][2];
  bf16x8 bF[2][2][2];

  const int T = K >> 6;

  // u: 0=A half0, 1=A half1, 2=B half0, 3=B half1
  auto stage = [&](int u, int kt) {
    const int b = kt & 1;
    if (u < 2) {
      const int off = b * 32768 + u * 16384 + ldsWj;
      __builtin_amdgcn_global_load_lds((AS1 void*)(aSt + (long)(u * 128) * K + kt * 64),
                                       (AS3 void*)(lds + off), 16, 0, 0);
      __builtin_amdgcn_global_load_lds((AS1 void*)(aSt + (long)(u * 128 + 8) * K + kt * 64),
                                       (AS3 void*)(lds + off + 1024), 16, 0, 0);
    } else {
      const int h = u - 2;
      const int off = 65536 + b * 32768 + h * 16384 + ldsWj;
      __builtin_amdgcn_global_load_lds((AS1 void*)(bSt + (long)(cb_j0 + h * 32) * K + kt * 64),
                                       (AS3 void*)(lds + off), 16, 0, 0);
      __builtin_amdgcn_global_load_lds((AS1 void*)(bSt + (long)(cb_j1 + h * 32) * K + kt * 64),
                                       (AS3 void*)(lds + off + 1024), 16, 0, 0);
    }
  };
  auto readA = [&](int qh, int b) {
    const int base = b * 32768 + qh * 16384 + aRdRow;
    #pragma unroll
    for (int fr = 0; fr < 4; ++fr) {
      aF[fr][0] = *(const bf16x8*)(lds + base + fr * 2048 + ck0);
      aF[fr][1] = *(const bf16x8*)(lds + base + fr * 2048 + (ck0 ^ 64));
    }
  };
  auto readB = [&](int c, int b) {
    const int base = 65536 + b * 32768 + c * 16384 + bRdRow;
    #pragma unroll
    for (int fq = 0; fq < 2; ++fq) {
      bF[c][fq][0] = *(const bf16x8*)(lds + base + fq * 2048 + ck0);
      bF[c][fq][1] = *(const bf16x8*)(lds + base + fq * 2048 + (ck0 ^ 64));
    }
  };
  auto mmac = [&](int qh, int c) {
    __builtin_amdgcn_s_setprio(1);
    #pragma unroll
    for (int fr = 0; fr < 4; ++fr)
      #pragma unroll
      for (int fq = 0; fq < 2; ++fq) {
        acc[qh * 4 + fr][c * 2 + fq] = __builtin_amdgcn_mfma_f32_16x16x32_bf16(
            aF[fr][0], bF[c][fq][0], acc[qh * 4 + fr][c * 2 + fq], 0, 0, 0);
        acc[qh * 4 + fr][c * 2 + fq] = __builtin_amdgcn_mfma_f32_16x16x32_bf16(
            aF[fr][1], bF[c][fq][1], acc[qh * 4 + fr][c * 2 + fq], 0, 0, 0);
      }
    __builtin_amdgcn_s_setprio(0);
  };

  // prologue: tiles 0,1 in issue order A0B0 | B1 | A1 per tile
  stage(0, 0); stage(2, 0); stage(3, 0); stage(1, 0);
  stage(0, 1); stage(2, 1); stage(3, 1); stage(1, 1);
  VMW(12);   // tile0 A0,B0 landed
  BAR();

  for (int t = 0; t < T - 2; ++t) {
    const int b = t & 1;
    // q0
    readA(0, b); readB(0, b); if (t) stage(1, t + 1);
    VMW(10); BAR(); LGKM0(); mmac(0, 0);
    // q1
    readB(1, b);
    VMW(8); BAR(); LGKM0(); mmac(0, 1);
    // q2
    readA(1, b); stage(0, t + 2); stage(2, t + 2);
    BAR(); LGKM0(); mmac(1, 1);
    // q3 (registers only)
    stage(3, t + 2);
    VMW(10); BAR(); mmac(1, 0);
  }
  {  // t = T-2 (exact drain counts)
    const int b = (T - 2) & 1;
    readA(0, b); readB(0, b); stage(1, T - 1);
    VMW(10); BAR(); LGKM0(); mmac(0, 0);
    readB(1, b);
    VMW(8); BAR(); LGKM0(); mmac(0, 1);
    readA(1, b);
    BAR(); LGKM0(); mmac(1, 1);
    VMW(4); BAR(); mmac(1, 0);
  }
  {  // t = T-1
    const int b = (T - 1) & 1;
    readA(0, b); readB(0, b);
    VMW(2); BAR(); LGKM0(); mmac(0, 0);
    readB(1, b);
    VMW(0); BAR(); LGKM0(); mmac(0, 1);
    readA(1, b);
    BAR(); LGKM0(); mmac(1, 1);
    BAR(); mmac(1, 0);
  }

  // ---- epilogue: LDS-transposed FULL-LINE stores ----
  // acc value (i8,j,r): row = brow + (i8>>2)*128 + wm*64 + (i8&3)*16 + lhi*4 + r,
  //                     col = bcol + wn*64 + (j>>1)*32 + (j&1)*16 + l15.
  // Each wave transposes its 16x64 tile through its own 4KB LDS (wave-local,
  // lgkmcnt(0) only), then stores f32x4 per lane: 4 rows x 256B full lines.
  const int wcol = bcol + wn * 64;
  const long rbase = brow + wm * 64;
  char* eplds = lds + w * 4096;

  auto storeTileF32 = [&](int i8, float* dst, bool rope) {
    #pragma unroll
    for (int j = 0; j < 4; ++j)
      #pragma unroll
      for (int r = 0; r < 4; ++r) {
        float v = acc[i8][j][r];
        if (rope) {
          const long row = rbase + (i8 >> 2) * 128 + (i8 & 3) * 16 + lhi * 4 + r;
          const int d = (j >> 1) * 32 + (j & 1) * 16 + l15;
          const float rot = (j < 2) ? -acc[i8][j + 2][r] : acc[i8][j - 2][r];
          v = v * cosp[row * 64 + d] + rot * sinp[row * 64 + d];
        }
        *(float*)(eplds + (lhi * 4 + r) * 256 + ((j >> 1) * 32 + (j & 1) * 16 + l15) * 4) = v;
      }
    asm volatile("s_waitcnt lgkmcnt(0)" ::: "memory");
    #pragma unroll
    for (int t = 0; t < 4; ++t) {
      const int r16 = t * 4 + (lane >> 4);
      const f32x4 v = *(const f32x4*)(eplds + r16 * 256 + (lane & 15) * 16);
      const long row = rbase + (i8 >> 2) * 128 + (i8 & 3) * 16 + r16;
      __builtin_nontemporal_store(v, (f32x4*)(dst + row * 6720 + (lane & 15) * 4));
    }
  };
  auto storeTileBf16 = [&](int i8) {
    #pragma unroll
    for (int j = 0; j < 4; ++j)
      #pragma unroll
      for (int r = 0; r < 4; ++r)
        *(unsigned short*)(eplds + (lhi * 4 + r) * 128 +
                           ((j >> 1) * 32 + (j & 1) * 16 + l15) * 2) = f2bf(acc[i8][j][r]);
    asm volatile("s_waitcnt lgkmcnt(0)" ::: "memory");
    #pragma unroll
    for (int t = 0; t < 2; ++t) {
      const int r16 = t * 8 + (lane >> 3);
      const ui32x4 v = *(const ui32x4*)(eplds + r16 * 128 + (lane & 7) * 16);
      const long row = rbase + (i8 >> 2) * 128 + (i8 & 3) * 16 + r16;
      *(ui32x4*)((char*)qlora + (row * 1536 + wcol) * 2 + (lane & 7) * 16) = v;
    }
  };

  if constexpr (MODE == 0) {
    if (wcol < 1536) {          // q_lora bf16 (cached; re-read by launch2)
      #pragma unroll
      for (int i8 = 0; i8 < 8; ++i8) storeTileBf16(i8);
    } else {                    // compressed_kv -> out cols 6208..6719
      #pragma unroll
      for (int i8 = 0; i8 < 8; ++i8) storeTileF32(i8, out + wcol + 4672, false);
    }
  } else {
    if (isA2) {
      if (wn == 0) {            // k_pe + RoPE -> out cols 6144..6207
        #pragma unroll
        for (int i8 = 0; i8 < 8; ++i8) storeTileF32(i8, out + 6144, true);
      }                         // wn 1..3: pad cols, dropped
    } else if ((wcol % 192) != 128) {  // q_nope
      #pragma unroll
      for (int i8 = 0; i8 < 8; ++i8) storeTileF32(i8, out + wcol, false);
    } else {                    // q_pe 64-block + RoPE
      #pragma unroll
      for (int i8 = 0; i8 < 8; ++i8) storeTileF32(i8, out + wcol, true);
    }
  }
}

// ---------------- launch ----------------

extern "C" void kernel_launch(void* const* d_in, const int* in_sizes, int n_in,
                              void* d_out, int out_size, void* d_ws, size_t ws_size,
                              hipStream_t stream) {
  const float* x    = (const float*)d_in[0];
  const float* cosp = (const float*)d_in[1];
  const float* sinp = (const float*)d_in[2];
  const float* Wqa  = (const float*)d_in[3];
  const float* Wqb  = (const float*)d_in[4];
  const float* Wkva = (const float*)d_in[5];
  float* out = (float*)d_out;

  char* ws = (char*)d_ws;
  __hip_bfloat16* xb  = (__hip_bfloat16*)ws;
  __hip_bfloat16* w1  = (__hip_bfloat16*)(ws + 67108864L);
  __hip_bfloat16* wqb = (__hip_bfloat16*)(ws + 67108864L + 17825792L);
  unsigned short* ql  = (unsigned short*)(ws + 67108864L + 17825792L + 18874368L);

  cvt_bf16_kernel<<<2048, 256, 0, stream>>>(x,   (unsigned short*)xb,  8192L * 4096 / 4);
  cvt_bf16_kernel<<<1024, 256, 0, stream>>>(Wqa, (unsigned short*)w1,  1536L * 4096 / 4);
  cvt_pad_kernel<<<640, 256, 0, stream>>>(Wkva, (unsigned short*)(w1 + 1536L * 4096),
                                          576L * 4096 / 4, 640L * 4096 / 4);
  cvt_bf16_kernel<<<1024, 256, 0, stream>>>(Wqb, (unsigned short*)wqb, 6144L * 1536 / 4);

  (void)hipFuncSetAttribute((const void*)&mla_gemm<0>,
                            hipFuncAttributeMaxDynamicSharedMemorySize, 131072);
  (void)hipFuncSetAttribute((const void*)&mla_gemm<1>,
                            hipFuncAttributeMaxDynamicSharedMemorySize, 131072);

  // launch1: x @ w1[0:2048] -> q_lora + compressed_kv. 256 blocks (1 round).
  mla_gemm<0><<<dim3(256), 512, 131072, stream>>>(xb, w1, 4096, nullptr, nullptr,
                                                  ql, cosp, sinp, out);
  // launch2: 32 k_pe blocks (K=4096, dispatched first = LPT) + 768 q blocks (K=1536).
  mla_gemm<1><<<dim3(800), 512, 131072, stream>>>((const __hip_bfloat16*)ql, wqb, 1536,
                                                  xb, w1, ql, cosp, sinp, out);
}